// Round 1
// baseline (454.123 us; speedup 1.0000x reference)
//
#include <hip/hip_runtime.h>
#include <math.h>

// Problem constants
#define BBATCH 4
#define LSEQ   2048
#define DMODEL 256
#define DINNER 512
#define DSTATE 16
#define DTRANK 16
#define MROWS  (BBATCH * LSEQ)   // 8192
#define NCHUNK 16
#define LCHUNK (LSEQ / NCHUNK)   // 128

// Workspace layout (in floats)
#define OFF_H      ((size_t)0)
#define OFF_HCONV  (OFF_H     + (size_t)MROWS * DMODEL)        // 2,097,152
#define OFF_XZ     (OFF_HCONV + (size_t)MROWS * DMODEL)        // 4,194,304
#define OFF_XC     (OFF_XZ    + (size_t)MROWS * 2 * DINNER)    // 12,582,912
#define OFF_DELTA  (OFF_XC    + (size_t)MROWS * DINNER)        // 16,777,216
#define OFF_XDBL   (OFF_DELTA + (size_t)MROWS * DINNER)        // 20,971,520
#define OFF_Y      (OFF_XDBL  + (size_t)MROWS * 48)            // 21,364,736
#define OFF_AAGG   (OFF_Y     + (size_t)MROWS * DINNER)        // 25,559,040
#define OFF_BAGG   (OFF_AAGG  + (size_t)BBATCH*DINNER*DSTATE*NCHUNK)
#define OFF_HINIT  (OFF_BAGG  + (size_t)BBATCH*DINNER*DSTATE*NCHUNK)
#define OFF_WTIN   (OFF_HINIT + (size_t)BBATCH*DINNER*DSTATE*NCHUNK)
#define OFF_WTCONV (OFF_WTIN   + (size_t)256 * 1024)
#define OFF_WTX    (OFF_WTCONV + (size_t)768 * 256)
#define OFF_WTDT   (OFF_WTX    + (size_t)512 * 48)
#define OFF_WTOUT  (OFF_WTDT   + (size_t)16 * 512)
// END = OFF_WTOUT + 512*256 = 27,754,496 floats = ~111 MB

__device__ __forceinline__ float silu_f(float v) {
  return v / (1.0f + __expf(-v));
}

// ---------------- weight repack (transpose for coalesced GEMM B access) ----
__global__ __launch_bounds__(256) void k_repack(
    const float* __restrict__ inw, const float* __restrict__ convw,
    const float* __restrict__ xw, const float* __restrict__ dtw,
    const float* __restrict__ ow, float* __restrict__ ws) {
  int idx = blockIdx.x * 256 + threadIdx.x;
  // Wt_in[k*1024+n] = inw[n*256+k]   (262144)
  if (idx < 262144) {
    int k = idx >> 10, n = idx & 1023;
    ws[OFF_WTIN + idx] = inw[n * 256 + k];
    return;
  }
  int i2 = idx - 262144;
  // Wt_conv[(kk*256+i)*256+o] = convw[(o*256+i)*3+kk]   (196608)
  if (i2 < 196608) {
    int o = i2 & 255, r = i2 >> 8;       // r = kk*256+i
    int kk = r >> 8, i = r & 255;
    ws[OFF_WTCONV + i2] = convw[(o * 256 + i) * 3 + kk];
    return;
  }
  int i3 = i2 - 196608;
  // Wt_x[k*48+n] = xw[n*512+k]   (24576)
  if (i3 < 24576) {
    int k = i3 / 48, n = i3 - k * 48;
    ws[OFF_WTX + i3] = xw[n * 512 + k];
    return;
  }
  int i4 = i3 - 24576;
  // Wt_dt[r*512+n] = dtw[n*16+r]   (8192)
  if (i4 < 8192) {
    int r = i4 >> 9, n = i4 & 511;
    ws[OFF_WTDT + i4] = dtw[n * 16 + r];
    return;
  }
  int i5 = i4 - 8192;
  // Wt_out[k*256+n] = ow[n*512+k]   (131072)
  if (i5 < 131072) {
    int k = i5 >> 8, n = i5 & 255;
    ws[OFF_WTOUT + i5] = ow[n * 512 + k];
  }
}

// ---------------- layernorm: one wave per row of 256 ------------------------
__global__ __launch_bounds__(256) void k_layernorm(
    const float* __restrict__ x, const float* __restrict__ w,
    const float* __restrict__ b, float* __restrict__ h) {
  int wave = threadIdx.x >> 6;
  int lane = threadIdx.x & 63;
  int row  = blockIdx.x * 4 + wave;  // < 8192
  const float4* xr = reinterpret_cast<const float4*>(x + (size_t)row * 256);
  float4 v = xr[lane];
  float s  = v.x + v.y + v.z + v.w;
  float sq = v.x*v.x + v.y*v.y + v.z*v.z + v.w*v.w;
  #pragma unroll
  for (int o = 32; o >= 1; o >>= 1) { s += __shfl_xor(s, o); sq += __shfl_xor(sq, o); }
  float mu  = s * (1.0f / 256.0f);
  float var = sq * (1.0f / 256.0f) - mu * mu;
  float rs  = rsqrtf(var + 1e-5f);
  float4 wv = reinterpret_cast<const float4*>(w)[lane];
  float4 bv = reinterpret_cast<const float4*>(b)[lane];
  float4 o4;
  o4.x = (v.x - mu) * rs * wv.x + bv.x;
  o4.y = (v.y - mu) * rs * wv.y + bv.y;
  o4.z = (v.z - mu) * rs * wv.z + bv.z;
  o4.w = (v.w - mu) * rs * wv.w + bv.w;
  reinterpret_cast<float4*>(h + (size_t)row * 256)[lane] = o4;
}

// ---------------- generic fp32 64x64 tile GEMM bodies ------------------------
// in_proj: C[8192,1024] = h[8192,256] @ Wt_in[256,1024]
__global__ __launch_bounds__(256) void k_gemm_inproj(
    const float* __restrict__ A, const float* __restrict__ Bt,
    float* __restrict__ C) {
  __shared__ float As[16][68];
  __shared__ float Bs[16][68];
  int tid = threadIdx.x;
  int m0 = blockIdx.x * 64, n0 = blockIdx.y * 64;
  int ar = tid >> 2, ac = (tid & 3) * 4;
  int br = tid >> 4, bc = (tid & 15) * 4;
  int tx = tid & 15, ty = tid >> 4;
  float acc[4][4] = {};
  for (int k0 = 0; k0 < 256; k0 += 16) {
    float4 av = *reinterpret_cast<const float4*>(A + (size_t)(m0 + ar) * 256 + k0 + ac);
    As[ac + 0][ar] = av.x; As[ac + 1][ar] = av.y;
    As[ac + 2][ar] = av.z; As[ac + 3][ar] = av.w;
    *reinterpret_cast<float4*>(&Bs[br][bc]) =
        *reinterpret_cast<const float4*>(Bt + (size_t)(k0 + br) * 1024 + n0 + bc);
    __syncthreads();
    #pragma unroll
    for (int kt = 0; kt < 16; ++kt) {
      float4 a = *reinterpret_cast<const float4*>(&As[kt][ty * 4]);
      float4 b = *reinterpret_cast<const float4*>(&Bs[kt][tx * 4]);
      acc[0][0]+=a.x*b.x; acc[0][1]+=a.x*b.y; acc[0][2]+=a.x*b.z; acc[0][3]+=a.x*b.w;
      acc[1][0]+=a.y*b.x; acc[1][1]+=a.y*b.y; acc[1][2]+=a.y*b.z; acc[1][3]+=a.y*b.w;
      acc[2][0]+=a.z*b.x; acc[2][1]+=a.z*b.y; acc[2][2]+=a.z*b.z; acc[2][3]+=a.z*b.w;
      acc[3][0]+=a.w*b.x; acc[3][1]+=a.w*b.y; acc[3][2]+=a.w*b.z; acc[3][3]+=a.w*b.w;
    }
    __syncthreads();
  }
  #pragma unroll
  for (int i = 0; i < 4; ++i) {
    float4 cv = make_float4(acc[i][0], acc[i][1], acc[i][2], acc[i][3]);
    *reinterpret_cast<float4*>(C + (size_t)(m0 + ty * 4 + i) * 1024 + n0 + tx * 4) = cv;
  }
}

// conv branch: virtual A[m, kk*256+i] = h[b, t-2+kk, i]; C = GELU(A@Wt_conv + cb)
__global__ __launch_bounds__(256) void k_gemm_conv(
    const float* __restrict__ h, const float* __restrict__ Bt,
    const float* __restrict__ cb, float* __restrict__ hconv) {
  __shared__ float As[16][68];
  __shared__ float Bs[16][68];
  int tid = threadIdx.x;
  int m0 = blockIdx.x * 64, n0 = blockIdx.y * 64;
  int bidx = m0 >> 11;          // whole tile same batch
  int t0 = m0 & 2047;
  int ar = tid >> 2, ac = (tid & 3) * 4;
  int br = tid >> 4, bc = (tid & 15) * 4;
  int tx = tid & 15, ty = tid >> 4;
  float acc[4][4] = {};
  for (int k0 = 0; k0 < 768; k0 += 16) {
    int kk = k0 >> 8, i0 = k0 & 255;
    int tt = t0 + ar - 2 + kk;
    float4 av = make_float4(0.f, 0.f, 0.f, 0.f);
    if (tt >= 0)
      av = *reinterpret_cast<const float4*>(h + ((size_t)(bidx * 2048 + tt)) * 256 + i0 + ac);
    As[ac + 0][ar] = av.x; As[ac + 1][ar] = av.y;
    As[ac + 2][ar] = av.z; As[ac + 3][ar] = av.w;
    *reinterpret_cast<float4*>(&Bs[br][bc]) =
        *reinterpret_cast<const float4*>(Bt + (size_t)(k0 + br) * 256 + n0 + bc);
    __syncthreads();
    #pragma unroll
    for (int kt = 0; kt < 16; ++kt) {
      float4 a = *reinterpret_cast<const float4*>(&As[kt][ty * 4]);
      float4 b = *reinterpret_cast<const float4*>(&Bs[kt][tx * 4]);
      acc[0][0]+=a.x*b.x; acc[0][1]+=a.x*b.y; acc[0][2]+=a.x*b.z; acc[0][3]+=a.x*b.w;
      acc[1][0]+=a.y*b.x; acc[1][1]+=a.y*b.y; acc[1][2]+=a.y*b.z; acc[1][3]+=a.y*b.w;
      acc[2][0]+=a.z*b.x; acc[2][1]+=a.z*b.y; acc[2][2]+=a.z*b.z; acc[2][3]+=a.z*b.w;
      acc[3][0]+=a.w*b.x; acc[3][1]+=a.w*b.y; acc[3][2]+=a.w*b.z; acc[3][3]+=a.w*b.w;
    }
    __syncthreads();
  }
  #pragma unroll
  for (int i = 0; i < 4; ++i) {
    float4 cv;
    #pragma unroll
    for (int j = 0; j < 4; ++j) {
      int n = n0 + tx * 4 + j;
      float v = acc[i][j] + cb[n];
      float g = 0.5f * v * (1.0f + erff(v * 0.70710678118654752440f));
      (&cv.x)[j] = g;
    }
    *reinterpret_cast<float4*>(hconv + (size_t)(m0 + ty * 4 + i) * 256 + n0 + tx * 4) = cv;
  }
}

// x_proj: C[8192,48] = xc[8192,512] @ Wt_x[512,48]
__global__ __launch_bounds__(256) void k_gemm_xproj(
    const float* __restrict__ A, const float* __restrict__ Bt,
    float* __restrict__ C) {
  __shared__ float As[16][68];
  __shared__ float Bs[16][68];
  int tid = threadIdx.x;
  int m0 = blockIdx.x * 64;
  int ar = tid >> 2, ac = (tid & 3) * 4;
  int br = tid >> 4, bc = (tid & 15) * 4;
  int tx = tid & 15, ty = tid >> 4;
  float acc[4][4] = {};
  for (int k0 = 0; k0 < 512; k0 += 16) {
    float4 av = *reinterpret_cast<const float4*>(A + (size_t)(m0 + ar) * 512 + k0 + ac);
    As[ac + 0][ar] = av.x; As[ac + 1][ar] = av.y;
    As[ac + 2][ar] = av.z; As[ac + 3][ar] = av.w;
    float4 bv = make_float4(0.f, 0.f, 0.f, 0.f);
    if (bc < 48)
      bv = *reinterpret_cast<const float4*>(Bt + (size_t)(k0 + br) * 48 + bc);
    *reinterpret_cast<float4*>(&Bs[br][bc]) = bv;
    __syncthreads();
    #pragma unroll
    for (int kt = 0; kt < 16; ++kt) {
      float4 a = *reinterpret_cast<const float4*>(&As[kt][ty * 4]);
      float4 b = *reinterpret_cast<const float4*>(&Bs[kt][tx * 4]);
      acc[0][0]+=a.x*b.x; acc[0][1]+=a.x*b.y; acc[0][2]+=a.x*b.z; acc[0][3]+=a.x*b.w;
      acc[1][0]+=a.y*b.x; acc[1][1]+=a.y*b.y; acc[1][2]+=a.y*b.z; acc[1][3]+=a.y*b.w;
      acc[2][0]+=a.z*b.x; acc[2][1]+=a.z*b.y; acc[2][2]+=a.z*b.z; acc[2][3]+=a.z*b.w;
      acc[3][0]+=a.w*b.x; acc[3][1]+=a.w*b.y; acc[3][2]+=a.w*b.z; acc[3][3]+=a.w*b.w;
    }
    __syncthreads();
  }
  if (tx < 12) {
    #pragma unroll
    for (int i = 0; i < 4; ++i) {
      float4 cv = make_float4(acc[i][0], acc[i][1], acc[i][2], acc[i][3]);
      *reinterpret_cast<float4*>(C + (size_t)(m0 + ty * 4 + i) * 48 + tx * 4) = cv;
    }
  }
}

// out_proj + final combine: out = x + 0.5*(y@Wt_out) + 0.5*hconv
__global__ __launch_bounds__(256) void k_gemm_outproj(
    const float* __restrict__ A, const float* __restrict__ Bt,
    const float* __restrict__ x, const float* __restrict__ hconv,
    float* __restrict__ out) {
  __shared__ float As[16][68];
  __shared__ float Bs[16][68];
  int tid = threadIdx.x;
  int m0 = blockIdx.x * 64, n0 = blockIdx.y * 64;
  int ar = tid >> 2, ac = (tid & 3) * 4;
  int br = tid >> 4, bc = (tid & 15) * 4;
  int tx = tid & 15, ty = tid >> 4;
  float acc[4][4] = {};
  for (int k0 = 0; k0 < 512; k0 += 16) {
    float4 av = *reinterpret_cast<const float4*>(A + (size_t)(m0 + ar) * 512 + k0 + ac);
    As[ac + 0][ar] = av.x; As[ac + 1][ar] = av.y;
    As[ac + 2][ar] = av.z; As[ac + 3][ar] = av.w;
    *reinterpret_cast<float4*>(&Bs[br][bc]) =
        *reinterpret_cast<const float4*>(Bt + (size_t)(k0 + br) * 256 + n0 + bc);
    __syncthreads();
    #pragma unroll
    for (int kt = 0; kt < 16; ++kt) {
      float4 a = *reinterpret_cast<const float4*>(&As[kt][ty * 4]);
      float4 b = *reinterpret_cast<const float4*>(&Bs[kt][tx * 4]);
      acc[0][0]+=a.x*b.x; acc[0][1]+=a.x*b.y; acc[0][2]+=a.x*b.z; acc[0][3]+=a.x*b.w;
      acc[1][0]+=a.y*b.x; acc[1][1]+=a.y*b.y; acc[1][2]+=a.y*b.z; acc[1][3]+=a.y*b.w;
      acc[2][0]+=a.z*b.x; acc[2][1]+=a.z*b.y; acc[2][2]+=a.z*b.z; acc[2][3]+=a.z*b.w;
      acc[3][0]+=a.w*b.x; acc[3][1]+=a.w*b.y; acc[3][2]+=a.w*b.z; acc[3][3]+=a.w*b.w;
    }
    __syncthreads();
  }
  #pragma unroll
  for (int i = 0; i < 4; ++i) {
    size_t off = (size_t)(m0 + ty * 4 + i) * 256 + n0 + tx * 4;
    float4 xv = *reinterpret_cast<const float4*>(x + off);
    float4 hv = *reinterpret_cast<const float4*>(hconv + off);
    float4 cv;
    cv.x = xv.x + 0.5f * acc[i][0] + 0.5f * hv.x;
    cv.y = xv.y + 0.5f * acc[i][1] + 0.5f * hv.y;
    cv.z = xv.z + 0.5f * acc[i][2] + 0.5f * hv.z;
    cv.w = xv.w + 0.5f * acc[i][3] + 0.5f * hv.w;
    *reinterpret_cast<float4*>(out + off) = cv;
  }
}

// ---------------- depthwise causal conv (DCONV=4) + SiLU --------------------
__global__ __launch_bounds__(256) void k_dwconv(
    const float* __restrict__ xz, const float* __restrict__ cw,
    const float* __restrict__ cb, float* __restrict__ xc) {
  int idx = blockIdx.x * 256 + threadIdx.x;   // over 8192*512
  int di = idx & 511;
  int m  = idx >> 9;
  int t  = m & 2047;
  float w0 = cw[di * 4 + 0], w1 = cw[di * 4 + 1];
  float w2 = cw[di * 4 + 2], w3 = cw[di * 4 + 3];
  const float* base = xz + (size_t)m * 1024 + di;
  float acc = cb[di] + w3 * base[0];
  if (t >= 1) acc += w2 * base[-1024];
  if (t >= 2) acc += w1 * base[-2048];
  if (t >= 3) acc += w0 * base[-3072];
  xc[(size_t)m * 512 + di] = silu_f(acc);
}

// ---------------- dt_proj + softplus ----------------------------------------
__global__ __launch_bounds__(256) void k_dtproj(
    const float* __restrict__ xdbl, const float* __restrict__ Wdt,
    const float* __restrict__ db, float* __restrict__ delta) {
  int m = blockIdx.x;   // 8192
  __shared__ float dts[16];
  if (threadIdx.x < 16) dts[threadIdx.x] = xdbl[(size_t)m * 48 + threadIdx.x];
  __syncthreads();
  for (int di = threadIdx.x; di < 512; di += 256) {
    float acc = db[di];
    #pragma unroll
    for (int r = 0; r < 16; ++r) acc += dts[r] * Wdt[r * 512 + di];
    delta[(size_t)m * 512 + di] = (acc > 20.0f) ? acc : log1pf(__expf(acc));
  }
}

// ---------------- chunked scan ----------------------------------------------
// pass 1: per-chunk affine aggregates (h_end = Ap*h_start + Bp)
__global__ __launch_bounds__(256) void k_scan1(
    const float* __restrict__ delta, const float* __restrict__ xdbl,
    const float* __restrict__ xc, const float* __restrict__ Alog,
    float* __restrict__ Aagg, float* __restrict__ Bagg) {
  int g = blockIdx.x * 256 + threadIdx.x;  // [c][b][di][s]
  int s  = g & 15;
  int di = (g >> 4) & 511;
  int b  = (g >> 13) & 3;
  int c  = g >> 15;
  float nA = -__expf(Alog[di * 16 + s]);
  int t0 = c * LCHUNK;
  const float* dp = delta + ((size_t)(b * 2048 + t0)) * 512 + di;
  const float* xp = xc    + ((size_t)(b * 2048 + t0)) * 512 + di;
  const float* bp = xdbl  + ((size_t)(b * 2048 + t0)) * 48 + 16 + s;
  float ap = 1.0f, bacc = 0.0f;
  for (int t = 0; t < LCHUNK; ++t) {
    float dv  = dp[(size_t)t * 512];
    float dA  = __expf(dv * nA);
    float dBx = dv * bp[(size_t)t * 48] * xp[(size_t)t * 512];
    bacc = dA * bacc + dBx;
    ap  *= dA;
  }
  size_t ag = ((size_t)((b * 512 + di) * 16 + s)) * NCHUNK + c;
  Aagg[ag] = ap;
  Bagg[ag] = bacc;
}

// pass 2: sequential combine over chunks -> per-chunk initial state
__global__ __launch_bounds__(256) void k_scan2(
    const float* __restrict__ Aagg, const float* __restrict__ Bagg,
    float* __restrict__ Hinit) {
  int g = blockIdx.x * 256 + threadIdx.x;  // 32768 = (b,di,s)
  float h = 0.0f;
  #pragma unroll
  for (int c = 0; c < NCHUNK; ++c) {
    Hinit[(size_t)g * NCHUNK + c] = h;
    h = Aagg[(size_t)g * NCHUNK + c] * h + Bagg[(size_t)g * NCHUNK + c];
  }
}

// pass 3: re-scan with correct init; fused y = (scan + xc*D) * silu(z)
__global__ __launch_bounds__(256) void k_scan3(
    const float* __restrict__ delta, const float* __restrict__ xdbl,
    const float* __restrict__ xc, const float* __restrict__ xz,
    const float* __restrict__ Alog, const float* __restrict__ Dp,
    const float* __restrict__ Hinit, float* __restrict__ y) {
  int g = blockIdx.x * 256 + threadIdx.x;
  int s  = g & 15;
  int di = (g >> 4) & 511;
  int b  = (g >> 13) & 3;
  int c  = g >> 15;
  float nA = -__expf(Alog[di * 16 + s]);
  float Dv = Dp[di];
  int t0 = c * LCHUNK;
  const float* dp = delta + ((size_t)(b * 2048 + t0)) * 512 + di;
  const float* xp = xc    + ((size_t)(b * 2048 + t0)) * 512 + di;
  const float* bp = xdbl  + ((size_t)(b * 2048 + t0)) * 48 + 16 + s;
  const float* cp = xdbl  + ((size_t)(b * 2048 + t0)) * 48 + 32 + s;
  const float* zp = xz    + ((size_t)(b * 2048 + t0)) * 1024 + 512 + di;
  float h = Hinit[((size_t)((b * 512 + di) * 16 + s)) * NCHUNK + c];
  for (int t = 0; t < LCHUNK; ++t) {
    float dv  = dp[(size_t)t * 512];
    float xcv = xp[(size_t)t * 512];
    float dA  = __expf(dv * nA);
    h = dA * h + dv * bp[(size_t)t * 48] * xcv;
    float p = h * cp[(size_t)t * 48];
    p += __shfl_xor(p, 8, 16);
    p += __shfl_xor(p, 4, 16);
    p += __shfl_xor(p, 2, 16);
    p += __shfl_xor(p, 1, 16);
    if (s == 0) {
      float yv = p + xcv * Dv;
      float zv = zp[(size_t)t * 1024];
      y[((size_t)(b * 2048 + t0 + t)) * 512 + di] = yv * silu_f(zv);
    }
  }
}

// ---------------- host launcher ---------------------------------------------
extern "C" void kernel_launch(void* const* d_in, const int* in_sizes, int n_in,
                              void* d_out, int out_size, void* d_ws, size_t ws_size,
                              hipStream_t stream) {
  const float* x     = (const float*)d_in[0];
  const float* lnw   = (const float*)d_in[1];
  const float* lnb   = (const float*)d_in[2];
  const float* convw = (const float*)d_in[3];
  const float* convb = (const float*)d_in[4];
  const float* inw   = (const float*)d_in[5];
  const float* c1w   = (const float*)d_in[6];
  const float* c1b   = (const float*)d_in[7];
  const float* xw    = (const float*)d_in[8];
  const float* dtw   = (const float*)d_in[9];
  const float* dtb   = (const float*)d_in[10];
  const float* alog  = (const float*)d_in[11];
  const float* Dp    = (const float*)d_in[12];
  const float* ow    = (const float*)d_in[13];
  float* ws  = (float*)d_ws;
  float* out = (float*)d_out;

  float* h     = ws + OFF_H;
  float* hconv = ws + OFF_HCONV;
  float* xzb   = ws + OFF_XZ;
  float* xc    = ws + OFF_XC;
  float* delta = ws + OFF_DELTA;
  float* xdbl  = ws + OFF_XDBL;
  float* y     = ws + OFF_Y;
  float* Aagg  = ws + OFF_AAGG;
  float* Bagg  = ws + OFF_BAGG;
  float* Hinit = ws + OFF_HINIT;
  float* Wtin  = ws + OFF_WTIN;
  float* Wtcv  = ws + OFF_WTCONV;
  float* Wtx   = ws + OFF_WTX;
  float* Wtdt  = ws + OFF_WTDT;
  float* Wtout = ws + OFF_WTOUT;

  k_repack<<<2432, 256, 0, stream>>>(inw, convw, xw, dtw, ow, ws);
  k_layernorm<<<2048, 256, 0, stream>>>(x, lnw, lnb, h);
  k_gemm_conv<<<dim3(128, 4), 256, 0, stream>>>(h, Wtcv, convb, hconv);
  k_gemm_inproj<<<dim3(128, 16), 256, 0, stream>>>(h, Wtin, xzb);
  k_dwconv<<<16384, 256, 0, stream>>>(xzb, c1w, c1b, xc);
  k_gemm_xproj<<<dim3(128, 1), 256, 0, stream>>>(xc, Wtx, xdbl);
  k_dtproj<<<8192, 256, 0, stream>>>(xdbl, Wtdt, dtb, delta);
  k_scan1<<<2048, 256, 0, stream>>>(delta, xdbl, xc, alog, Aagg, Bagg);
  k_scan2<<<128, 256, 0, stream>>>(Aagg, Bagg, Hinit);
  k_scan3<<<2048, 256, 0, stream>>>(delta, xdbl, xc, xzb, alog, Dp, Hinit, y);
  k_gemm_outproj<<<dim3(128, 4), 256, 0, stream>>>(y, Wtout, x, hconv, out);
}

// Round 5
// 375.271 us; speedup vs baseline: 1.2101x; 1.2101x over previous
//
#include <hip/hip_runtime.h>
#include <math.h>

// Problem constants
#define BBATCH 4
#define LSEQ   2048
#define DMODEL 256
#define DINNER 512
#define DSTATE 16
#define DTRANK 16
#define MROWS  (BBATCH * LSEQ)   // 8192
#define NCHUNK 64
#define LCHUNK (LSEQ / NCHUNK)   // 32

// Workspace layout (in floats)
#define OFF_H      ((size_t)0)                                  // dead after in_proj -> reused as AAGG/HINIT
#define OFF_HCONV  (OFF_H     + (size_t)MROWS * DMODEL)         // 2,097,152
#define OFF_XIN    (OFF_HCONV + (size_t)MROWS * DMODEL)         // 4,194,304  dead after dwconv -> reused as BAGG
#define OFF_Z      (OFF_XIN   + (size_t)MROWS * DINNER)         // 8,388,608
#define OFF_XC     (OFF_Z     + (size_t)MROWS * DINNER)         // 12,582,912
#define OFF_DELTA  (OFF_XC    + (size_t)MROWS * DINNER)         // 16,777,216
#define OFF_XDBL   (OFF_DELTA + (size_t)MROWS * DINNER)         // 20,971,520
#define OFF_Y      (OFF_XDBL  + (size_t)MROWS * 48)             // 21,364,736
#define OFF_WTIN   (OFF_Y     + (size_t)MROWS * DINNER)         // 25,559,040
#define OFF_WTCONV (OFF_WTIN   + (size_t)256 * 1024)
#define OFF_WTX    (OFF_WTCONV + (size_t)768 * 256)
#define OFF_WTDT   (OFF_WTX    + (size_t)512 * 48)
#define OFF_WTOUT  (OFF_WTDT   + (size_t)16 * 512)
// END = OFF_WTOUT + 512*256 = 26,181,632 floats = ~104.7 MB
#define OFF_AAGG   OFF_H      // 4*64*16*512 = 2,097,152 floats, fits exactly
#define OFF_BAGG   OFF_XIN
#define OFF_HINIT  OFF_AAGG   // scan2 reads Aagg[idx] before writing Hinit[idx]

__device__ __forceinline__ float silu_f(float v) {
  return v / (1.0f + __expf(-v));
}

// ---------------- weight repack (transpose for coalesced GEMM B access) ----
__global__ __launch_bounds__(256) void k_repack(
    const float* __restrict__ inw, const float* __restrict__ convw,
    const float* __restrict__ xw, const float* __restrict__ dtw,
    const float* __restrict__ ow, float* __restrict__ ws) {
  int idx = blockIdx.x * 256 + threadIdx.x;
  if (idx < 262144) {  // Wt_in[k*1024+n] = inw[n*256+k]
    int k = idx >> 10, n = idx & 1023;
    ws[OFF_WTIN + idx] = inw[n * 256 + k];
    return;
  }
  int i2 = idx - 262144;
  if (i2 < 196608) {   // Wt_conv[(kk*256+i)*256+o] = convw[(o*256+i)*3+kk]
    int o = i2 & 255, r = i2 >> 8;
    int kk = r >> 8, i = r & 255;
    ws[OFF_WTCONV + i2] = convw[(o * 256 + i) * 3 + kk];
    return;
  }
  int i3 = i2 - 196608;
  if (i3 < 24576) {    // Wt_x[k*48+n] = xw[n*512+k]
    int k = i3 / 48, n = i3 - k * 48;
    ws[OFF_WTX + i3] = xw[n * 512 + k];
    return;
  }
  int i4 = i3 - 24576;
  if (i4 < 8192) {     // Wt_dt[r*512+n] = dtw[n*16+r]
    int r = i4 >> 9, n = i4 & 511;
    ws[OFF_WTDT + i4] = dtw[n * 16 + r];
    return;
  }
  int i5 = i4 - 8192;
  if (i5 < 131072) {   // Wt_out[k*256+n] = ow[n*512+k]
    int k = i5 >> 8, n = i5 & 255;
    ws[OFF_WTOUT + i5] = ow[n * 512 + k];
  }
}

// ---------------- layernorm: one wave per row of 256 ------------------------
__global__ __launch_bounds__(256) void k_layernorm(
    const float* __restrict__ x, const float* __restrict__ w,
    const float* __restrict__ b, float* __restrict__ h) {
  int wave = threadIdx.x >> 6;
  int lane = threadIdx.x & 63;
  int row  = blockIdx.x * 4 + wave;  // < 8192
  const float4* xr = reinterpret_cast<const float4*>(x + (size_t)row * 256);
  float4 v = xr[lane];
  float s  = v.x + v.y + v.z + v.w;
  float sq = v.x*v.x + v.y*v.y + v.z*v.z + v.w*v.w;
  #pragma unroll
  for (int o = 32; o >= 1; o >>= 1) { s += __shfl_xor(s, o); sq += __shfl_xor(sq, o); }
  float mu  = s * (1.0f / 256.0f);
  float var = sq * (1.0f / 256.0f) - mu * mu;
  float rs  = rsqrtf(var + 1e-5f);
  float4 wv = reinterpret_cast<const float4*>(w)[lane];
  float4 bv = reinterpret_cast<const float4*>(b)[lane];
  float4 o4;
  o4.x = (v.x - mu) * rs * wv.x + bv.x;
  o4.y = (v.y - mu) * rs * wv.y + bv.y;
  o4.z = (v.z - mu) * rs * wv.z + bv.z;
  o4.w = (v.w - mu) * rs * wv.w + bv.w;
  reinterpret_cast<float4*>(h + (size_t)row * 256)[lane] = o4;
}

// ---------------- fp32 64x64 tile GEMMs ------------------------
// in_proj: C[8192,1024] = h[8192,256] @ Wt_in[256,1024]; split cols into xin/z
__global__ __launch_bounds__(256) void k_gemm_inproj(
    const float* __restrict__ A, const float* __restrict__ Bt,
    float* __restrict__ xin, float* __restrict__ z) {
  __shared__ float As[16][68];
  __shared__ float Bs[16][68];
  int tid = threadIdx.x;
  int m0 = blockIdx.x * 64, n0 = blockIdx.y * 64;
  int ar = tid >> 2, ac = (tid & 3) * 4;
  int br = tid >> 4, bc = (tid & 15) * 4;
  int tx = tid & 15, ty = tid >> 4;
  float acc[4][4] = {};
  for (int k0 = 0; k0 < 256; k0 += 16) {
    float4 av = *reinterpret_cast<const float4*>(A + (size_t)(m0 + ar) * 256 + k0 + ac);
    As[ac + 0][ar] = av.x; As[ac + 1][ar] = av.y;
    As[ac + 2][ar] = av.z; As[ac + 3][ar] = av.w;
    *reinterpret_cast<float4*>(&Bs[br][bc]) =
        *reinterpret_cast<const float4*>(Bt + (size_t)(k0 + br) * 1024 + n0 + bc);
    __syncthreads();
    #pragma unroll
    for (int kt = 0; kt < 16; ++kt) {
      float4 a = *reinterpret_cast<const float4*>(&As[kt][ty * 4]);
      float4 b = *reinterpret_cast<const float4*>(&Bs[kt][tx * 4]);
      acc[0][0]+=a.x*b.x; acc[0][1]+=a.x*b.y; acc[0][2]+=a.x*b.z; acc[0][3]+=a.x*b.w;
      acc[1][0]+=a.y*b.x; acc[1][1]+=a.y*b.y; acc[1][2]+=a.y*b.z; acc[1][3]+=a.y*b.w;
      acc[2][0]+=a.z*b.x; acc[2][1]+=a.z*b.y; acc[2][2]+=a.z*b.z; acc[2][3]+=a.z*b.w;
      acc[3][0]+=a.w*b.x; acc[3][1]+=a.w*b.y; acc[3][2]+=a.w*b.z; acc[3][3]+=a.w*b.w;
    }
    __syncthreads();
  }
  float* dst = (n0 < 512) ? xin : z;
  int nc = (n0 < 512) ? n0 : (n0 - 512);
  #pragma unroll
  for (int i = 0; i < 4; ++i) {
    float4 cv = make_float4(acc[i][0], acc[i][1], acc[i][2], acc[i][3]);
    *reinterpret_cast<float4*>(dst + (size_t)(m0 + ty * 4 + i) * 512 + nc + tx * 4) = cv;
  }
}

// conv branch: virtual A[m, kk*256+i] = h[b, t-2+kk, i]; C = GELU(A@Wt_conv + cb)
__global__ __launch_bounds__(256) void k_gemm_conv(
    const float* __restrict__ h, const float* __restrict__ Bt,
    const float* __restrict__ cb, float* __restrict__ hconv) {
  __shared__ float As[16][68];
  __shared__ float Bs[16][68];
  int tid = threadIdx.x;
  int m0 = blockIdx.x * 64, n0 = blockIdx.y * 64;
  int bidx = m0 >> 11;
  int t0 = m0 & 2047;
  int ar = tid >> 2, ac = (tid & 3) * 4;
  int br = tid >> 4, bc = (tid & 15) * 4;
  int tx = tid & 15, ty = tid >> 4;
  float acc[4][4] = {};
  for (int k0 = 0; k0 < 768; k0 += 16) {
    int kk = k0 >> 8, i0 = k0 & 255;
    int tt = t0 + ar - 2 + kk;
    float4 av = make_float4(0.f, 0.f, 0.f, 0.f);
    if (tt >= 0)
      av = *reinterpret_cast<const float4*>(h + ((size_t)(bidx * 2048 + tt)) * 256 + i0 + ac);
    As[ac + 0][ar] = av.x; As[ac + 1][ar] = av.y;
    As[ac + 2][ar] = av.z; As[ac + 3][ar] = av.w;
    *reinterpret_cast<float4*>(&Bs[br][bc]) =
        *reinterpret_cast<const float4*>(Bt + (size_t)(k0 + br) * 256 + n0 + bc);
    __syncthreads();
    #pragma unroll
    for (int kt = 0; kt < 16; ++kt) {
      float4 a = *reinterpret_cast<const float4*>(&As[kt][ty * 4]);
      float4 b = *reinterpret_cast<const float4*>(&Bs[kt][tx * 4]);
      acc[0][0]+=a.x*b.x; acc[0][1]+=a.x*b.y; acc[0][2]+=a.x*b.z; acc[0][3]+=a.x*b.w;
      acc[1][0]+=a.y*b.x; acc[1][1]+=a.y*b.y; acc[1][2]+=a.y*b.z; acc[1][3]+=a.y*b.w;
      acc[2][0]+=a.z*b.x; acc[2][1]+=a.z*b.y; acc[2][2]+=a.z*b.z; acc[2][3]+=a.z*b.w;
      acc[3][0]+=a.w*b.x; acc[3][1]+=a.w*b.y; acc[3][2]+=a.w*b.z; acc[3][3]+=a.w*b.w;
    }
    __syncthreads();
  }
  #pragma unroll
  for (int i = 0; i < 4; ++i) {
    float4 cv;
    #pragma unroll
    for (int j = 0; j < 4; ++j) {
      int n = n0 + tx * 4 + j;
      float v = acc[i][j] + cb[n];
      float g = 0.5f * v * (1.0f + erff(v * 0.70710678118654752440f));
      (&cv.x)[j] = g;
    }
    *reinterpret_cast<float4*>(hconv + (size_t)(m0 + ty * 4 + i) * 256 + n0 + tx * 4) = cv;
  }
}

// x_proj: C[8192,48] = xc[8192,512] @ Wt_x[512,48]
__global__ __launch_bounds__(256) void k_gemm_xproj(
    const float* __restrict__ A, const float* __restrict__ Bt,
    float* __restrict__ C) {
  __shared__ float As[16][68];
  __shared__ float Bs[16][68];
  int tid = threadIdx.x;
  int m0 = blockIdx.x * 64;
  int ar = tid >> 2, ac = (tid & 3) * 4;
  int br = tid >> 4, bc = (tid & 15) * 4;
  int tx = tid & 15, ty = tid >> 4;
  float acc[4][4] = {};
  for (int k0 = 0; k0 < 512; k0 += 16) {
    float4 av = *reinterpret_cast<const float4*>(A + (size_t)(m0 + ar) * 512 + k0 + ac);
    As[ac + 0][ar] = av.x; As[ac + 1][ar] = av.y;
    As[ac + 2][ar] = av.z; As[ac + 3][ar] = av.w;
    float4 bv = make_float4(0.f, 0.f, 0.f, 0.f);
    if (bc < 48)
      bv = *reinterpret_cast<const float4*>(Bt + (size_t)(k0 + br) * 48 + bc);
    *reinterpret_cast<float4*>(&Bs[br][bc]) = bv;
    __syncthreads();
    #pragma unroll
    for (int kt = 0; kt < 16; ++kt) {
      float4 a = *reinterpret_cast<const float4*>(&As[kt][ty * 4]);
      float4 b = *reinterpret_cast<const float4*>(&Bs[kt][tx * 4]);
      acc[0][0]+=a.x*b.x; acc[0][1]+=a.x*b.y; acc[0][2]+=a.x*b.z; acc[0][3]+=a.x*b.w;
      acc[1][0]+=a.y*b.x; acc[1][1]+=a.y*b.y; acc[1][2]+=a.y*b.z; acc[1][3]+=a.y*b.w;
      acc[2][0]+=a.z*b.x; acc[2][1]+=a.z*b.y; acc[2][2]+=a.z*b.z; acc[2][3]+=a.z*b.w;
      acc[3][0]+=a.w*b.x; acc[3][1]+=a.w*b.y; acc[3][2]+=a.w*b.z; acc[3][3]+=a.w*b.w;
    }
    __syncthreads();
  }
  if (tx < 12) {
    #pragma unroll
    for (int i = 0; i < 4; ++i) {
      float4 cv = make_float4(acc[i][0], acc[i][1], acc[i][2], acc[i][3]);
      *reinterpret_cast<float4*>(C + (size_t)(m0 + ty * 4 + i) * 48 + tx * 4) = cv;
    }
  }
}

// out_proj + final combine: out = x + 0.5*(y@Wt_out) + 0.5*hconv
__global__ __launch_bounds__(256) void k_gemm_outproj(
    const float* __restrict__ A, const float* __restrict__ Bt,
    const float* __restrict__ x, const float* __restrict__ hconv,
    float* __restrict__ out) {
  __shared__ float As[16][68];
  __shared__ float Bs[16][68];
  int tid = threadIdx.x;
  int m0 = blockIdx.x * 64, n0 = blockIdx.y * 64;
  int ar = tid >> 2, ac = (tid & 3) * 4;
  int br = tid >> 4, bc = (tid & 15) * 4;
  int tx = tid & 15, ty = tid >> 4;
  float acc[4][4] = {};
  for (int k0 = 0; k0 < 512; k0 += 16) {
    float4 av = *reinterpret_cast<const float4*>(A + (size_t)(m0 + ar) * 512 + k0 + ac);
    As[ac + 0][ar] = av.x; As[ac + 1][ar] = av.y;
    As[ac + 2][ar] = av.z; As[ac + 3][ar] = av.w;
    *reinterpret_cast<float4*>(&Bs[br][bc]) =
        *reinterpret_cast<const float4*>(Bt + (size_t)(k0 + br) * 256 + n0 + bc);
    __syncthreads();
    #pragma unroll
    for (int kt = 0; kt < 16; ++kt) {
      float4 a = *reinterpret_cast<const float4*>(&As[kt][ty * 4]);
      float4 b = *reinterpret_cast<const float4*>(&Bs[kt][tx * 4]);
      acc[0][0]+=a.x*b.x; acc[0][1]+=a.x*b.y; acc[0][2]+=a.x*b.z; acc[0][3]+=a.x*b.w;
      acc[1][0]+=a.y*b.x; acc[1][1]+=a.y*b.y; acc[1][2]+=a.y*b.z; acc[1][3]+=a.y*b.w;
      acc[2][0]+=a.z*b.x; acc[2][1]+=a.z*b.y; acc[2][2]+=a.z*b.z; acc[2][3]+=a.z*b.w;
      acc[3][0]+=a.w*b.x; acc[3][1]+=a.w*b.y; acc[3][2]+=a.w*b.z; acc[3][3]+=a.w*b.w;
    }
    __syncthreads();
  }
  #pragma unroll
  for (int i = 0; i < 4; ++i) {
    size_t off = (size_t)(m0 + ty * 4 + i) * 256 + n0 + tx * 4;
    float4 xv = *reinterpret_cast<const float4*>(x + off);
    float4 hv = *reinterpret_cast<const float4*>(hconv + off);
    float4 cv;
    cv.x = xv.x + 0.5f * acc[i][0] + 0.5f * hv.x;
    cv.y = xv.y + 0.5f * acc[i][1] + 0.5f * hv.y;
    cv.z = xv.z + 0.5f * acc[i][2] + 0.5f * hv.z;
    cv.w = xv.w + 0.5f * acc[i][3] + 0.5f * hv.w;
    *reinterpret_cast<float4*>(out + off) = cv;
  }
}

// ---------------- depthwise causal conv (DCONV=4) + SiLU --------------------
__global__ __launch_bounds__(256) void k_dwconv(
    const float* __restrict__ xin, const float* __restrict__ cw,
    const float* __restrict__ cb, float* __restrict__ xc) {
  int idx = blockIdx.x * 256 + threadIdx.x;   // over 8192*512
  int di = idx & 511;
  int m  = idx >> 9;
  int t  = m & 2047;
  float w0 = cw[di * 4 + 0], w1 = cw[di * 4 + 1];
  float w2 = cw[di * 4 + 2], w3 = cw[di * 4 + 3];
  const float* base = xin + (size_t)m * 512 + di;
  float acc = cb[di] + w3 * base[0];
  if (t >= 1) acc += w2 * base[-512];
  if (t >= 2) acc += w1 * base[-1024];
  if (t >= 3) acc += w0 * base[-1536];
  xc[(size_t)m * 512 + di] = silu_f(acc);
}

// ---------------- dt_proj + softplus ----------------------------------------
__global__ __launch_bounds__(256) void k_dtproj(
    const float* __restrict__ xdbl, const float* __restrict__ Wdt,
    const float* __restrict__ db, float* __restrict__ delta) {
  int m = blockIdx.x;   // 8192
  __shared__ float dts[16];
  if (threadIdx.x < 16) dts[threadIdx.x] = xdbl[(size_t)m * 48 + threadIdx.x];
  __syncthreads();
  for (int di = threadIdx.x; di < 512; di += 256) {
    float acc = db[di];
    #pragma unroll
    for (int r = 0; r < 16; ++r) acc += dts[r] * Wdt[r * 512 + di];
    delta[(size_t)m * 512 + di] = (acc > 20.0f) ? acc : log1pf(__expf(acc));
  }
}

// ---------------- chunked scan: thread-per-(b,chunk,di), 16 states in regs --
// pass 1: per-chunk affine aggregates (h_end = Ap*h_start + Bp)
__global__ __launch_bounds__(256) void k_scan1(
    const float* __restrict__ delta, const float* __restrict__ xdbl,
    const float* __restrict__ xc, const float* __restrict__ Alog,
    float* __restrict__ Aagg, float* __restrict__ Bagg) {
  int di = ((blockIdx.x & 1) << 8) | threadIdx.x;   // 0..511
  int c  = (blockIdx.x >> 1) & 63;                  // chunk (uniform per block)
  int b  = blockIdx.x >> 7;                         // batch (uniform per block)
  float nA[16];
  #pragma unroll
  for (int q = 0; q < 4; ++q) {
    float4 v = *reinterpret_cast<const float4*>(Alog + (size_t)di * 16 + q * 4);
    nA[q*4+0] = -__expf(v.x); nA[q*4+1] = -__expf(v.y);
    nA[q*4+2] = -__expf(v.z); nA[q*4+3] = -__expf(v.w);
  }
  float ap[16], bacc[16];
  #pragma unroll
  for (int s = 0; s < 16; ++s) { ap[s] = 1.0f; bacc[s] = 0.0f; }
  int row0 = b * 2048 + c * LCHUNK;
  const float* dp = delta + (size_t)row0 * 512 + di;
  const float* xp = xc    + (size_t)row0 * 512 + di;
  const float* Bp = xdbl  + (size_t)row0 * 48 + 16;   // uniform address stream
  #pragma unroll 2
  for (int t = 0; t < LCHUNK; ++t) {
    float dv = dp[t * 512];
    float u  = dv * xp[t * 512];
    #pragma unroll
    for (int s = 0; s < 16; ++s) {
      float e = __expf(dv * nA[s]);
      ap[s]   *= e;
      bacc[s]  = e * bacc[s] + u * Bp[t * 48 + s];
    }
  }
  size_t base = ((size_t)((b * 64 + c) * 16)) * 512 + di;  // [b][c][s][di]
  #pragma unroll
  for (int s = 0; s < 16; ++s) {
    Aagg[base + (size_t)s * 512] = ap[s];
    Bagg[base + (size_t)s * 512] = bacc[s];
  }
}

// pass 2: sequential combine over chunks -> per-chunk initial state
// NOTE: Hinit aliases Aagg; read Aagg[idx] BEFORE writing Hinit[idx] (same thread)
__global__ __launch_bounds__(256) void k_scan2(
    const float* __restrict__ Aagg, const float* __restrict__ Bagg,
    float* __restrict__ Hinit) {
  int g  = blockIdx.x * 256 + threadIdx.x;  // 32768 = [b][s][di]
  int di = g & 511, s = (g >> 9) & 15, b = g >> 13;
  float h = 0.0f;
  for (int c = 0; c < NCHUNK; ++c) {
    size_t idx = ((size_t)((b * 64 + c) * 16 + s)) * 512 + di;
    float a = Aagg[idx], bb = Bagg[idx];
    Hinit[idx] = h;
    h = a * h + bb;
  }
}

// pass 3: re-scan with correct init; fused y = (scan + xc*D) * silu(z)
__global__ __launch_bounds__(256) void k_scan3(
    const float* __restrict__ delta, const float* __restrict__ xdbl,
    const float* __restrict__ xc, const float* __restrict__ z,
    const float* __restrict__ Alog, const float* __restrict__ Dp,
    const float* __restrict__ Hinit, float* __restrict__ y) {
  int di = ((blockIdx.x & 1) << 8) | threadIdx.x;
  int c  = (blockIdx.x >> 1) & 63;
  int b  = blockIdx.x >> 7;
  float nA[16];
  #pragma unroll
  for (int q = 0; q < 4; ++q) {
    float4 v = *reinterpret_cast<const float4*>(Alog + (size_t)di * 16 + q * 4);
    nA[q*4+0] = -__expf(v.x); nA[q*4+1] = -__expf(v.y);
    nA[q*4+2] = -__expf(v.z); nA[q*4+3] = -__expf(v.w);
  }
  float h[16];
  size_t hb = ((size_t)((b * 64 + c) * 16)) * 512 + di;
  #pragma unroll
  for (int s = 0; s < 16; ++s) h[s] = Hinit[hb + (size_t)s * 512];
  float Dv = Dp[di];
  int row0 = b * 2048 + c * LCHUNK;
  const float* dp = delta + (size_t)row0 * 512 + di;
  const float* xp = xc    + (size_t)row0 * 512 + di;
  const float* zp = z     + (size_t)row0 * 512 + di;
  const float* Bp = xdbl  + (size_t)row0 * 48 + 16;
  const float* Cp = xdbl  + (size_t)row0 * 48 + 32;
  float* yp       = y     + (size_t)row0 * 512 + di;
  #pragma unroll 2
  for (int t = 0; t < LCHUNK; ++t) {
    float dv  = dp[t * 512];
    float xcv = xp[t * 512];
    float u   = dv * xcv;
    float yv  = 0.0f;
    #pragma unroll
    for (int s = 0; s < 16; ++s) {
      float e = __expf(dv * nA[s]);
      h[s] = e * h[s] + u * Bp[t * 48 + s];
      yv  += h[s] * Cp[t * 48 + s];
    }
    yv += xcv * Dv;
    float zv = zp[t * 512];
    yp[t * 512] = yv * silu_f(zv);
  }
}

// ---------------- host launcher ---------------------------------------------
extern "C" void kernel_launch(void* const* d_in, const int* in_sizes, int n_in,
                              void* d_out, int out_size, void* d_ws, size_t ws_size,
                              hipStream_t stream) {
  const float* x     = (const float*)d_in[0];
  const float* lnw   = (const float*)d_in[1];
  const float* lnb   = (const float*)d_in[2];
  const float* convw = (const float*)d_in[3];
  const float* convb = (const float*)d_in[4];
  const float* inw   = (const float*)d_in[5];
  const float* c1w   = (const float*)d_in[6];
  const float* c1b   = (const float*)d_in[7];
  const float* xw    = (const float*)d_in[8];
  const float* dtw   = (const float*)d_in[9];
  const float* dtb   = (const float*)d_in[10];
  const float* alog  = (const float*)d_in[11];
  const float* Dp    = (const float*)d_in[12];
  const float* ow    = (const float*)d_in[13];
  float* ws  = (float*)d_ws;
  float* out = (float*)d_out;

  float* h     = ws + OFF_H;
  float* hconv = ws + OFF_HCONV;
  float* xin   = ws + OFF_XIN;
  float* zb    = ws + OFF_Z;
  float* xc    = ws + OFF_XC;
  float* delta = ws + OFF_DELTA;
  float* xdbl  = ws + OFF_XDBL;
  float* y     = ws + OFF_Y;
  float* Aagg  = ws + OFF_AAGG;
  float* Bagg  = ws + OFF_BAGG;
  float* Hinit = ws + OFF_HINIT;
  float* Wtin  = ws + OFF_WTIN;
  float* Wtcv  = ws + OFF_WTCONV;
  float* Wtx   = ws + OFF_WTX;
  float* Wtdt  = ws + OFF_WTDT;
  float* Wtout = ws + OFF_WTOUT;

  k_repack<<<2432, 256, 0, stream>>>(inw, convw, xw, dtw, ow, ws);
  k_layernorm<<<2048, 256, 0, stream>>>(x, lnw, lnb, h);
  k_gemm_conv<<<dim3(128, 4), 256, 0, stream>>>(h, Wtcv, convb, hconv);
  k_gemm_inproj<<<dim3(128, 16), 256, 0, stream>>>(h, Wtin, xin, zb);
  k_dwconv<<<16384, 256, 0, stream>>>(xin, c1w, c1b, xc);
  k_gemm_xproj<<<dim3(128, 1), 256, 0, stream>>>(xc, Wtx, xdbl);
  k_dtproj<<<8192, 256, 0, stream>>>(xdbl, Wtdt, dtb, delta);
  k_scan1<<<512, 256, 0, stream>>>(delta, xdbl, xc, alog, Aagg, Bagg);
  k_scan2<<<128, 256, 0, stream>>>(Aagg, Bagg, Hinit);
  k_scan3<<<512, 256, 0, stream>>>(delta, xdbl, xc, zb, alog, Dp, Hinit, y);
  k_gemm_outproj<<<dim3(128, 4), 256, 0, stream>>>(y, Wtout, x, hconv, out);
}

// Round 6
// 254.044 us; speedup vs baseline: 1.7876x; 1.4772x over previous
//
#include <hip/hip_runtime.h>
#include <math.h>

// Problem constants
#define BBATCH 4
#define LSEQ   2048
#define DMODEL 256
#define DINNER 512
#define DSTATE 16
#define DTRANK 16
#define MROWS  (BBATCH * LSEQ)   // 8192
#define NCHUNK 64
#define LCHUNK (LSEQ / NCHUNK)   // 32

typedef unsigned short u16;
typedef __attribute__((ext_vector_type(8))) short bf16x8;   // 8 bf16 in 4 VGPRs (guide §3)
typedef __attribute__((ext_vector_type(4))) float f32x4;

// Workspace layout (float units). END = 26,935,296 fl = 107.7 MB (< 111 MB proven OK)
#define OFF_HBF    ((size_t)0)            // 8192*256 bf16  = 1,048,576 fl
#define OFF_HCONV  ((size_t)1048576)      // 2,097,152 fl
#define OFF_XIN    ((size_t)3145728)      // 4,194,304 fl
#define OFF_Z      ((size_t)7340032)      // 4,194,304 fl
#define OFF_XC     ((size_t)11534336)     // 4,194,304 fl
#define OFF_DELTA  ((size_t)15728640)     // 4,194,304 fl
#define OFF_XDBL   ((size_t)19922944)     //   393,216 fl
#define OFF_YBF    ((size_t)20316160)     // 8192*512 bf16 = 2,097,152 fl
#define OFF_AAGG   ((size_t)22413312)     // 2,097,152 fl
#define OFF_BAGG   ((size_t)24510464)     // 2,097,152 fl
#define OFF_HINIT  OFF_AAGG               // scan2 reads Aagg[idx] before writing Hinit[idx]
#define OFF_WTINBF ((size_t)26607616)     // 1024*256 bf16 = 131,072 fl
#define OFF_WTCVBF ((size_t)26738688)     //  256*768 bf16 =  98,304 fl
#define OFF_WTOUTBF ((size_t)26836992)    //  256*512 bf16 =  65,536 fl
#define OFF_WTX    ((size_t)26902528)     //  24,576 fl
#define OFF_WTDT   ((size_t)26927104)     //   8,192 fl

__device__ __forceinline__ float silu_f(float v) {
  return v / (1.0f + __expf(-v));
}
__device__ __forceinline__ u16 f2bf(float f) {   // RNE float->bf16
  unsigned u = __float_as_uint(f);
  return (u16)((u + 0x7FFFu + ((u >> 16) & 1u)) >> 16);
}

// ---------------- weight repack (+ fp32->bf16 casts) -------------------------
__global__ __launch_bounds__(256) void k_repack(
    const float* __restrict__ inw, const float* __restrict__ convw,
    const float* __restrict__ xw, const float* __restrict__ dtw,
    const float* __restrict__ ow, float* __restrict__ ws) {
  int idx = blockIdx.x * 256 + threadIdx.x;
  u16* win  = (u16*)(ws + OFF_WTINBF);
  u16* wcv  = (u16*)(ws + OFF_WTCVBF);
  u16* wout = (u16*)(ws + OFF_WTOUTBF);
  float* wx  = ws + OFF_WTX;
  float* wdt = ws + OFF_WTDT;
  if (idx < 262144) {            // Wt_in_bf[n][k] = inw[n][k] (layout identical)
    win[idx] = f2bf(inw[idx]);
    return;
  }
  int i2 = idx - 262144;
  if (i2 < 196608) {             // Wt_conv_bf[o][kk*256+i] = convw[(o*256+i)*3+kk]
    int o = i2 / 768, r = i2 - o * 768;
    int kk = r >> 8, i = r & 255;
    wcv[i2] = f2bf(convw[(o * 256 + i) * 3 + kk]);
    return;
  }
  int i3 = i2 - 196608;
  if (i3 < 131072) {             // Wt_out_bf[n][k] = ow[n][k]
    wout[i3] = f2bf(ow[i3]);
    return;
  }
  int i4 = i3 - 131072;
  if (i4 < 24576) {              // Wt_x[k*48+n] = xw[n*512+k] (fp32)
    int k = i4 / 48, n = i4 - k * 48;
    wx[i4] = xw[n * 512 + k];
    return;
  }
  int i5 = i4 - 24576;
  if (i5 < 8192) {               // Wt_dt[r*512+n] = dtw[n*16+r] (fp32)
    int r = i5 >> 9, n = i5 & 511;
    wdt[i5] = dtw[n * 16 + r];
  }
}

// ---------------- layernorm: one wave per row of 256; bf16 output ------------
__global__ __launch_bounds__(256) void k_layernorm(
    const float* __restrict__ x, const float* __restrict__ w,
    const float* __restrict__ b, u16* __restrict__ hb) {
  int wave = threadIdx.x >> 6;
  int lane = threadIdx.x & 63;
  int row  = blockIdx.x * 4 + wave;  // < 8192
  const float4* xr = reinterpret_cast<const float4*>(x + (size_t)row * 256);
  float4 v = xr[lane];
  float s  = v.x + v.y + v.z + v.w;
  float sq = v.x*v.x + v.y*v.y + v.z*v.z + v.w*v.w;
  #pragma unroll
  for (int o = 32; o >= 1; o >>= 1) { s += __shfl_xor(s, o); sq += __shfl_xor(sq, o); }
  float mu  = s * (1.0f / 256.0f);
  float var = sq * (1.0f / 256.0f) - mu * mu;
  float rs  = rsqrtf(var + 1e-5f);
  float4 wv = reinterpret_cast<const float4*>(w)[lane];
  float4 bv = reinterpret_cast<const float4*>(b)[lane];
  ushort4 o4;
  o4.x = f2bf((v.x - mu) * rs * wv.x + bv.x);
  o4.y = f2bf((v.y - mu) * rs * wv.y + bv.y);
  o4.z = f2bf((v.z - mu) * rs * wv.z + bv.z);
  o4.w = f2bf((v.w - mu) * rs * wv.w + bv.w);
  reinterpret_cast<ushort4*>(hb + (size_t)row * 256)[lane] = o4;
}

// ================= bf16 MFMA GEMMs: 64x64 tile, 4 waves (2x2), BK=64 ========
// LDS tiles padded to 72 bf16/row (144 B stride -> 2-way bank alias, free).
// A frag: row=lane&15, k=(lane>>4)*8+b. B stored n-major ([n][k]) so B frag is
// the verified "B^T" pattern. C/D: col=lane&15, row=(lane>>4)*4+reg (m89).

// in_proj: C[8192,1024] = h_bf[8192,256] @ Wt_in_bf[1024,256]^T; split xin/z
__global__ __launch_bounds__(256) void k_bgemm_inproj(
    const u16* __restrict__ Abf, const u16* __restrict__ Bbf,
    float* __restrict__ xin, float* __restrict__ z) {
  __shared__ __align__(16) u16 As[64 * 72];
  __shared__ __align__(16) u16 Bs[64 * 72];
  int tid = threadIdx.x;
  int m0 = blockIdx.x * 64, n0 = blockIdx.y * 64;
  int lane = tid & 63, wid = tid >> 6;
  int wr = (wid >> 1) * 32, wc = (wid & 1) * 32;
  int l15 = lane & 15, lk = (lane >> 4) * 8;
  int r0 = tid >> 3, kc = (tid & 7) * 8;
  f32x4 acc[2][2] = {};
  for (int k0 = 0; k0 < 256; k0 += 64) {
    *(bf16x8*)&As[r0 * 72 + kc] =
        *(const bf16x8*)&Abf[(size_t)(m0 + r0) * 256 + k0 + kc];
    *(bf16x8*)&As[(r0 + 32) * 72 + kc] =
        *(const bf16x8*)&Abf[(size_t)(m0 + r0 + 32) * 256 + k0 + kc];
    *(bf16x8*)&Bs[r0 * 72 + kc] =
        *(const bf16x8*)&Bbf[(size_t)(n0 + r0) * 256 + k0 + kc];
    *(bf16x8*)&Bs[(r0 + 32) * 72 + kc] =
        *(const bf16x8*)&Bbf[(size_t)(n0 + r0 + 32) * 256 + k0 + kc];
    __syncthreads();
    #pragma unroll
    for (int kk = 0; kk < 64; kk += 32) {
      bf16x8 a0 = *(const bf16x8*)&As[(wr + l15) * 72 + kk + lk];
      bf16x8 a1 = *(const bf16x8*)&As[(wr + 16 + l15) * 72 + kk + lk];
      bf16x8 b0 = *(const bf16x8*)&Bs[(wc + l15) * 72 + kk + lk];
      bf16x8 b1 = *(const bf16x8*)&Bs[(wc + 16 + l15) * 72 + kk + lk];
      acc[0][0] = __builtin_amdgcn_mfma_f32_16x16x32_bf16(a0, b0, acc[0][0], 0, 0, 0);
      acc[0][1] = __builtin_amdgcn_mfma_f32_16x16x32_bf16(a0, b1, acc[0][1], 0, 0, 0);
      acc[1][0] = __builtin_amdgcn_mfma_f32_16x16x32_bf16(a1, b0, acc[1][0], 0, 0, 0);
      acc[1][1] = __builtin_amdgcn_mfma_f32_16x16x32_bf16(a1, b1, acc[1][1], 0, 0, 0);
    }
    __syncthreads();
  }
  float* dst = (n0 < 512) ? xin : z;
  int nb = (n0 < 512) ? n0 : n0 - 512;
  int rowb = m0 + wr + (lane >> 4) * 4;
  #pragma unroll
  for (int mi = 0; mi < 2; ++mi)
    #pragma unroll
    for (int ni = 0; ni < 2; ++ni) {
      int gc = nb + wc + ni * 16 + l15;
      #pragma unroll
      for (int r = 0; r < 4; ++r)
        dst[(size_t)(rowb + mi * 16 + r) * 512 + gc] = acc[mi][ni][r];
    }
}

// conv branch: A = im2col(h_bf) [8192,768], B = Wt_conv_bf[256,768]; GELU out
__global__ __launch_bounds__(256) void k_bgemm_conv(
    const u16* __restrict__ hbf, const u16* __restrict__ Bbf,
    const float* __restrict__ cb, float* __restrict__ hconv) {
  __shared__ __align__(16) u16 As[64 * 72];
  __shared__ __align__(16) u16 Bs[64 * 72];
  int tid = threadIdx.x;
  int m0 = blockIdx.x * 64, n0 = blockIdx.y * 64;
  int bidx = m0 >> 11, t0 = m0 & 2047;
  int lane = tid & 63, wid = tid >> 6;
  int wr = (wid >> 1) * 32, wc = (wid & 1) * 32;
  int l15 = lane & 15, lk = (lane >> 4) * 8;
  int r0 = tid >> 3, kc = (tid & 7) * 8;
  f32x4 acc[2][2] = {};
  for (int k0 = 0; k0 < 768; k0 += 64) {
    int kkc = k0 >> 8;          // conv tap (constant within k-step since 64|256)
    int i0  = (k0 & 255) + kc;
    int t1  = t0 + r0 - 2 + kkc;
    bf16x8 av0 = {0, 0, 0, 0, 0, 0, 0, 0};
    if (t1 >= 0)
      av0 = *(const bf16x8*)&hbf[(size_t)((bidx << 11) + t1) * 256 + i0];
    bf16x8 av1 =                 // row r0+32: t' = t0+r0+30+kkc >= 30, no guard
        *(const bf16x8*)&hbf[(size_t)((bidx << 11) + t1 + 32) * 256 + i0];
    *(bf16x8*)&As[r0 * 72 + kc] = av0;
    *(bf16x8*)&As[(r0 + 32) * 72 + kc] = av1;
    *(bf16x8*)&Bs[r0 * 72 + kc] =
        *(const bf16x8*)&Bbf[(size_t)(n0 + r0) * 768 + k0 + kc];
    *(bf16x8*)&Bs[(r0 + 32) * 72 + kc] =
        *(const bf16x8*)&Bbf[(size_t)(n0 + r0 + 32) * 768 + k0 + kc];
    __syncthreads();
    #pragma unroll
    for (int kk = 0; kk < 64; kk += 32) {
      bf16x8 a0 = *(const bf16x8*)&As[(wr + l15) * 72 + kk + lk];
      bf16x8 a1 = *(const bf16x8*)&As[(wr + 16 + l15) * 72 + kk + lk];
      bf16x8 b0 = *(const bf16x8*)&Bs[(wc + l15) * 72 + kk + lk];
      bf16x8 b1 = *(const bf16x8*)&Bs[(wc + 16 + l15) * 72 + kk + lk];
      acc[0][0] = __builtin_amdgcn_mfma_f32_16x16x32_bf16(a0, b0, acc[0][0], 0, 0, 0);
      acc[0][1] = __builtin_amdgcn_mfma_f32_16x16x32_bf16(a0, b1, acc[0][1], 0, 0, 0);
      acc[1][0] = __builtin_amdgcn_mfma_f32_16x16x32_bf16(a1, b0, acc[1][0], 0, 0, 0);
      acc[1][1] = __builtin_amdgcn_mfma_f32_16x16x32_bf16(a1, b1, acc[1][1], 0, 0, 0);
    }
    __syncthreads();
  }
  int rowb = m0 + wr + (lane >> 4) * 4;
  #pragma unroll
  for (int mi = 0; mi < 2; ++mi)
    #pragma unroll
    for (int ni = 0; ni < 2; ++ni) {
      int gc = n0 + wc + ni * 16 + l15;
      float bias = cb[gc];
      #pragma unroll
      for (int r = 0; r < 4; ++r) {
        float v = acc[mi][ni][r] + bias;
        float g = 0.5f * v * (1.0f + erff(v * 0.70710678118654752440f));
        hconv[(size_t)(rowb + mi * 16 + r) * 256 + gc] = g;
      }
    }
}

// out_proj + combine: out = x + 0.5*(y_bf @ Wt_out_bf^T) + 0.5*hconv
__global__ __launch_bounds__(256) void k_bgemm_outproj(
    const u16* __restrict__ Abf, const u16* __restrict__ Bbf,
    const float* __restrict__ x, const float* __restrict__ hconv,
    float* __restrict__ out) {
  __shared__ __align__(16) u16 As[64 * 72];
  __shared__ __align__(16) u16 Bs[64 * 72];
  int tid = threadIdx.x;
  int m0 = blockIdx.x * 64, n0 = blockIdx.y * 64;
  int lane = tid & 63, wid = tid >> 6;
  int wr = (wid >> 1) * 32, wc = (wid & 1) * 32;
  int l15 = lane & 15, lk = (lane >> 4) * 8;
  int r0 = tid >> 3, kc = (tid & 7) * 8;
  f32x4 acc[2][2] = {};
  for (int k0 = 0; k0 < 512; k0 += 64) {
    *(bf16x8*)&As[r0 * 72 + kc] =
        *(const bf16x8*)&Abf[(size_t)(m0 + r0) * 512 + k0 + kc];
    *(bf16x8*)&As[(r0 + 32) * 72 + kc] =
        *(const bf16x8*)&Abf[(size_t)(m0 + r0 + 32) * 512 + k0 + kc];
    *(bf16x8*)&Bs[r0 * 72 + kc] =
        *(const bf16x8*)&Bbf[(size_t)(n0 + r0) * 512 + k0 + kc];
    *(bf16x8*)&Bs[(r0 + 32) * 72 + kc] =
        *(const bf16x8*)&Bbf[(size_t)(n0 + r0 + 32) * 512 + k0 + kc];
    __syncthreads();
    #pragma unroll
    for (int kk = 0; kk < 64; kk += 32) {
      bf16x8 a0 = *(const bf16x8*)&As[(wr + l15) * 72 + kk + lk];
      bf16x8 a1 = *(const bf16x8*)&As[(wr + 16 + l15) * 72 + kk + lk];
      bf16x8 b0 = *(const bf16x8*)&Bs[(wc + l15) * 72 + kk + lk];
      bf16x8 b1 = *(const bf16x8*)&Bs[(wc + 16 + l15) * 72 + kk + lk];
      acc[0][0] = __builtin_amdgcn_mfma_f32_16x16x32_bf16(a0, b0, acc[0][0], 0, 0, 0);
      acc[0][1] = __builtin_amdgcn_mfma_f32_16x16x32_bf16(a0, b1, acc[0][1], 0, 0, 0);
      acc[1][0] = __builtin_amdgcn_mfma_f32_16x16x32_bf16(a1, b0, acc[1][0], 0, 0, 0);
      acc[1][1] = __builtin_amdgcn_mfma_f32_16x16x32_bf16(a1, b1, acc[1][1], 0, 0, 0);
    }
    __syncthreads();
  }
  int rowb = m0 + wr + (lane >> 4) * 4;
  #pragma unroll
  for (int mi = 0; mi < 2; ++mi)
    #pragma unroll
    for (int ni = 0; ni < 2; ++ni) {
      int gc = n0 + wc + ni * 16 + l15;
      #pragma unroll
      for (int r = 0; r < 4; ++r) {
        size_t off = (size_t)(rowb + mi * 16 + r) * 256 + gc;
        out[off] = x[off] + 0.5f * acc[mi][ni][r] + 0.5f * hconv[off];
      }
    }
}

// x_proj (fp32, unchanged): C[8192,48] = xc[8192,512] @ Wt_x[512,48]
__global__ __launch_bounds__(256) void k_gemm_xproj(
    const float* __restrict__ A, const float* __restrict__ Bt,
    float* __restrict__ C) {
  __shared__ float As[16][68];
  __shared__ float Bs[16][68];
  int tid = threadIdx.x;
  int m0 = blockIdx.x * 64;
  int ar = tid >> 2, ac = (tid & 3) * 4;
  int br = tid >> 4, bc = (tid & 15) * 4;
  int tx = tid & 15, ty = tid >> 4;
  float acc[4][4] = {};
  for (int k0 = 0; k0 < 512; k0 += 16) {
    float4 av = *reinterpret_cast<const float4*>(A + (size_t)(m0 + ar) * 512 + k0 + ac);
    As[ac + 0][ar] = av.x; As[ac + 1][ar] = av.y;
    As[ac + 2][ar] = av.z; As[ac + 3][ar] = av.w;
    float4 bv = make_float4(0.f, 0.f, 0.f, 0.f);
    if (bc < 48)
      bv = *reinterpret_cast<const float4*>(Bt + (size_t)(k0 + br) * 48 + bc);
    *reinterpret_cast<float4*>(&Bs[br][bc]) = bv;
    __syncthreads();
    #pragma unroll
    for (int kt = 0; kt < 16; ++kt) {
      float4 a = *reinterpret_cast<const float4*>(&As[kt][ty * 4]);
      float4 b = *reinterpret_cast<const float4*>(&Bs[kt][tx * 4]);
      acc[0][0]+=a.x*b.x; acc[0][1]+=a.x*b.y; acc[0][2]+=a.x*b.z; acc[0][3]+=a.x*b.w;
      acc[1][0]+=a.y*b.x; acc[1][1]+=a.y*b.y; acc[1][2]+=a.y*b.z; acc[1][3]+=a.y*b.w;
      acc[2][0]+=a.z*b.x; acc[2][1]+=a.z*b.y; acc[2][2]+=a.z*b.z; acc[2][3]+=a.z*b.w;
      acc[3][0]+=a.w*b.x; acc[3][1]+=a.w*b.y; acc[3][2]+=a.w*b.z; acc[3][3]+=a.w*b.w;
    }
    __syncthreads();
  }
  if (tx < 12) {
    #pragma unroll
    for (int i = 0; i < 4; ++i) {
      float4 cv = make_float4(acc[i][0], acc[i][1], acc[i][2], acc[i][3]);
      *reinterpret_cast<float4*>(C + (size_t)(m0 + ty * 4 + i) * 48 + tx * 4) = cv;
    }
  }
}

// ---------------- depthwise causal conv (DCONV=4) + SiLU --------------------
__global__ __launch_bounds__(256) void k_dwconv(
    const float* __restrict__ xin, const float* __restrict__ cw,
    const float* __restrict__ cb, float* __restrict__ xc) {
  int idx = blockIdx.x * 256 + threadIdx.x;   // over 8192*512
  int di = idx & 511;
  int m  = idx >> 9;
  int t  = m & 2047;
  float w0 = cw[di * 4 + 0], w1 = cw[di * 4 + 1];
  float w2 = cw[di * 4 + 2], w3 = cw[di * 4 + 3];
  const float* base = xin + (size_t)m * 512 + di;
  float acc = cb[di] + w3 * base[0];
  if (t >= 1) acc += w2 * base[-512];
  if (t >= 2) acc += w1 * base[-1024];
  if (t >= 3) acc += w0 * base[-1536];
  xc[(size_t)m * 512 + di] = silu_f(acc);
}

// ---------------- dt_proj + softplus ----------------------------------------
__global__ __launch_bounds__(256) void k_dtproj(
    const float* __restrict__ xdbl, const float* __restrict__ Wdt,
    const float* __restrict__ db, float* __restrict__ delta) {
  int m = blockIdx.x;   // 8192
  __shared__ float dts[16];
  if (threadIdx.x < 16) dts[threadIdx.x] = xdbl[(size_t)m * 48 + threadIdx.x];
  __syncthreads();
  for (int di = threadIdx.x; di < 512; di += 256) {
    float acc = db[di];
    #pragma unroll
    for (int r = 0; r < 16; ++r) acc += dts[r] * Wdt[r * 512 + di];
    delta[(size_t)m * 512 + di] = (acc > 20.0f) ? acc : log1pf(__expf(acc));
  }
}

// ---------------- chunked scan: thread-per-(b,chunk,di), 16 states in regs --
__global__ __launch_bounds__(256) void k_scan1(
    const float* __restrict__ delta, const float* __restrict__ xdbl,
    const float* __restrict__ xc, const float* __restrict__ Alog,
    float* __restrict__ Aagg, float* __restrict__ Bagg) {
  int di = ((blockIdx.x & 1) << 8) | threadIdx.x;
  int c  = (blockIdx.x >> 1) & 63;
  int b  = blockIdx.x >> 7;
  float nA[16];
  #pragma unroll
  for (int q = 0; q < 4; ++q) {
    float4 v = *reinterpret_cast<const float4*>(Alog + (size_t)di * 16 + q * 4);
    nA[q*4+0] = -__expf(v.x); nA[q*4+1] = -__expf(v.y);
    nA[q*4+2] = -__expf(v.z); nA[q*4+3] = -__expf(v.w);
  }
  float ap[16], bacc[16];
  #pragma unroll
  for (int s = 0; s < 16; ++s) { ap[s] = 1.0f; bacc[s] = 0.0f; }
  int row0 = b * 2048 + c * LCHUNK;
  const float* dp = delta + (size_t)row0 * 512 + di;
  const float* xp = xc    + (size_t)row0 * 512 + di;
  const float* Bp = xdbl  + (size_t)row0 * 48 + 16;
  #pragma unroll 2
  for (int t = 0; t < LCHUNK; ++t) {
    float dv = dp[t * 512];
    float u  = dv * xp[t * 512];
    #pragma unroll
    for (int s = 0; s < 16; ++s) {
      float e = __expf(dv * nA[s]);
      ap[s]   *= e;
      bacc[s]  = e * bacc[s] + u * Bp[t * 48 + s];
    }
  }
  size_t base = ((size_t)((b * 64 + c) * 16)) * 512 + di;
  #pragma unroll
  for (int s = 0; s < 16; ++s) {
    Aagg[base + (size_t)s * 512] = ap[s];
    Bagg[base + (size_t)s * 512] = bacc[s];
  }
}

__global__ __launch_bounds__(256) void k_scan2(
    const float* __restrict__ Aagg, const float* __restrict__ Bagg,
    float* __restrict__ Hinit) {
  int g  = blockIdx.x * 256 + threadIdx.x;
  int di = g & 511, s = (g >> 9) & 15, b = g >> 13;
  float h = 0.0f;
  for (int c = 0; c < NCHUNK; ++c) {
    size_t idx = ((size_t)((b * 64 + c) * 16 + s)) * 512 + di;
    float a = Aagg[idx], bb = Bagg[idx];
    Hinit[idx] = h;
    h = a * h + bb;
  }
}

// pass 3: re-scan; fused y = (scan + xc*D) * silu(z); bf16 output for out_proj
__global__ __launch_bounds__(256) void k_scan3(
    const float* __restrict__ delta, const float* __restrict__ xdbl,
    const float* __restrict__ xc, const float* __restrict__ z,
    const float* __restrict__ Alog, const float* __restrict__ Dp,
    const float* __restrict__ Hinit, u16* __restrict__ y) {
  int di = ((blockIdx.x & 1) << 8) | threadIdx.x;
  int c  = (blockIdx.x >> 1) & 63;
  int b  = blockIdx.x >> 7;
  float nA[16];
  #pragma unroll
  for (int q = 0; q < 4; ++q) {
    float4 v = *reinterpret_cast<const float4*>(Alog + (size_t)di * 16 + q * 4);
    nA[q*4+0] = -__expf(v.x); nA[q*4+1] = -__expf(v.y);
    nA[q*4+2] = -__expf(v.z); nA[q*4+3] = -__expf(v.w);
  }
  float h[16];
  size_t hb = ((size_t)((b * 64 + c) * 16)) * 512 + di;
  #pragma unroll
  for (int s = 0; s < 16; ++s) h[s] = Hinit[hb + (size_t)s * 512];
  float Dv = Dp[di];
  int row0 = b * 2048 + c * LCHUNK;
  const float* dp = delta + (size_t)row0 * 512 + di;
  const float* xp = xc    + (size_t)row0 * 512 + di;
  const float* zp = z     + (size_t)row0 * 512 + di;
  const float* Bp = xdbl  + (size_t)row0 * 48 + 16;
  const float* Cp = xdbl  + (size_t)row0 * 48 + 32;
  u16* yp         = y     + (size_t)row0 * 512 + di;
  #pragma unroll 2
  for (int t = 0; t < LCHUNK; ++t) {
    float dv  = dp[t * 512];
    float xcv = xp[t * 512];
    float u   = dv * xcv;
    float yv  = 0.0f;
    #pragma unroll
    for (int s = 0; s < 16; ++s) {
      float e = __expf(dv * nA[s]);
      h[s] = e * h[s] + u * Bp[t * 48 + s];
      yv  += h[s] * Cp[t * 48 + s];
    }
    yv += xcv * Dv;
    float zv = zp[t * 512];
    yp[t * 512] = f2bf(yv * silu_f(zv));
  }
}

// ---------------- host launcher ---------------------------------------------
extern "C" void kernel_launch(void* const* d_in, const int* in_sizes, int n_in,
                              void* d_out, int out_size, void* d_ws, size_t ws_size,
                              hipStream_t stream) {
  const float* x     = (const float*)d_in[0];
  const float* lnw   = (const float*)d_in[1];
  const float* lnb   = (const float*)d_in[2];
  const float* convw = (const float*)d_in[3];
  const float* convb = (const float*)d_in[4];
  const float* inw   = (const float*)d_in[5];
  const float* c1w   = (const float*)d_in[6];
  const float* c1b   = (const float*)d_in[7];
  const float* xw    = (const float*)d_in[8];
  const float* dtw   = (const float*)d_in[9];
  const float* dtb   = (const float*)d_in[10];
  const float* alog  = (const float*)d_in[11];
  const float* Dp    = (const float*)d_in[12];
  const float* ow    = (const float*)d_in[13];
  float* ws  = (float*)d_ws;
  float* out = (float*)d_out;

  u16* hbf    = (u16*)(ws + OFF_HBF);
  float* hconv = ws + OFF_HCONV;
  float* xin   = ws + OFF_XIN;
  float* zb    = ws + OFF_Z;
  float* xc    = ws + OFF_XC;
  float* delta = ws + OFF_DELTA;
  float* xdbl  = ws + OFF_XDBL;
  u16* ybf    = (u16*)(ws + OFF_YBF);
  float* Aagg  = ws + OFF_AAGG;
  float* Bagg  = ws + OFF_BAGG;
  float* Hinit = ws + OFF_HINIT;
  u16* winbf  = (u16*)(ws + OFF_WTINBF);
  u16* wcvbf  = (u16*)(ws + OFF_WTCVBF);
  u16* woutbf = (u16*)(ws + OFF_WTOUTBF);
  float* Wtx   = ws + OFF_WTX;
  float* Wtdt  = ws + OFF_WTDT;

  k_repack<<<2432, 256, 0, stream>>>(inw, convw, xw, dtw, ow, ws);
  k_layernorm<<<2048, 256, 0, stream>>>(x, lnw, lnb, hbf);
  k_bgemm_conv<<<dim3(128, 4), 256, 0, stream>>>(hbf, wcvbf, convb, hconv);
  k_bgemm_inproj<<<dim3(128, 16), 256, 0, stream>>>(hbf, winbf, xin, zb);
  k_dwconv<<<16384, 256, 0, stream>>>(xin, c1w, c1b, xc);
  k_gemm_xproj<<<dim3(128, 1), 256, 0, stream>>>(xc, Wtx, xdbl);
  k_dtproj<<<8192, 256, 0, stream>>>(xdbl, Wtdt, dtb, delta);
  k_scan1<<<512, 256, 0, stream>>>(delta, xdbl, xc, alog, Aagg, Bagg);
  k_scan2<<<128, 256, 0, stream>>>(Aagg, Bagg, Hinit);
  k_scan3<<<512, 256, 0, stream>>>(delta, xdbl, xc, zb, alog, Dp, Hinit, ybf);
  k_bgemm_outproj<<<dim3(128, 4), 256, 0, stream>>>(ybf, woutbf, x, hconv, out);
}